// Round 2
// baseline (518.742 us; speedup 1.0000x reference)
//
#include <hip/hip_runtime.h>
#include <hip/hip_bf16.h>
#include <hip/hip_cooperative_groups.h>

namespace cg = cooperative_groups;

#define NNODES 8192
#define EMB    1024
#define HID    256
#define MAXDEG 128

typedef float f32x4 __attribute__((ext_vector_type(4)));
typedef short bf16x8v __attribute__((ext_vector_type(8)));
typedef unsigned short u16x4 __attribute__((ext_vector_type(4)));
typedef unsigned short u16x8 __attribute__((ext_vector_type(8)));

static __device__ __forceinline__ unsigned short f2bf(float f) {
  union { float f; unsigned int u; } x; x.f = f;
  unsigned int r = (x.u + 0x7fffu + ((x.u >> 16) & 1u)) >> 16;
  return (unsigned short)r;
}

// ---------------------------------------------------------------------------
// Prep: Wt[n][k] = bf16(W[k][n]).  64x64 f32 tiles via LDS transpose.
// Grid: (1024/64)*(256/64) = 64 blocks.
// ---------------------------------------------------------------------------
__global__ __launch_bounds__(256) void prep_wt(const float* __restrict__ W,
                                               unsigned short* __restrict__ Wt) {
  __shared__ float lds[64 * 65];
  int k0 = (blockIdx.x >> 2) * 64;
  int n0 = (blockIdx.x & 3) * 64;
  int t = threadIdx.x;
#pragma unroll
  for (int p = 0; p < 4; p++) {
    int k = p * 16 + (t >> 4);
    int c4 = (t & 15) * 4;
    float4 v = *(const float4*)&W[(size_t)(k0 + k) * HID + n0 + c4];
    lds[k * 65 + c4 + 0] = v.x; lds[k * 65 + c4 + 1] = v.y;
    lds[k * 65 + c4 + 2] = v.z; lds[k * 65 + c4 + 3] = v.w;
  }
  __syncthreads();
  int n = t >> 2, kq = t & 3;
  u16x8 o0, o1;
#pragma unroll
  for (int i = 0; i < 8; i++) o0[i] = f2bf(lds[(kq * 16 + i) * 65 + n]);
#pragma unroll
  for (int i = 0; i < 8; i++) o1[i] = f2bf(lds[(kq * 16 + 8 + i) * 65 + n]);
  unsigned short* dst = &Wt[(size_t)(n0 + n) * EMB + k0 + kq * 16];
  *(u16x8*)(dst) = o0;
  *(u16x8*)(dst + 8) = o1;
}

// ---------------------------------------------------------------------------
// Fused: blocks [0,256) do the bf16-MFMA GEMM h0 = relu(X@W+b);
// blocks [256, 256+8192) do adjacency extract (one row each).
// Independent work co-scheduled so GEMM compute hides under extract's HBM scan.
// ---------------------------------------------------------------------------
#define GEMM_BLOCKS 256

__global__ __launch_bounds__(256) void fused_extract_gemm(
    const float* __restrict__ X, const unsigned short* __restrict__ Wt,
    const float* __restrict__ bias, const float* __restrict__ adj,
    float* __restrict__ h0, float* __restrict__ dinv, int* __restrict__ nnz,
    int* __restrict__ cols, float* __restrict__ vals) {
  __shared__ char smem[24 * 1024 + 64];
  int t = threadIdx.x;

  if (blockIdx.x >= GEMM_BLOCKS) {
    // ---------------- extract path ----------------
    int row = blockIdx.x - GEMM_BLOCKS;
    int* s_cnt = (int*)smem;
    float* s_part = (float*)(smem + 16);
    if (t == 0) *s_cnt = 0;
    __syncthreads();
    const float4* arow = (const float4*)(adj + (size_t)row * NNODES);
    float sum = 0.f;
    int base = row * MAXDEG;
    for (int c4 = t; c4 < NNODES / 4; c4 += 256) {
      float4 v = arow[c4];
      sum += v.x + v.y + v.z + v.w;
      if (v.x != 0.f) { int p = atomicAdd(s_cnt, 1); if (p < MAXDEG) { cols[base + p] = c4 * 4 + 0; vals[base + p] = v.x; } }
      if (v.y != 0.f) { int p = atomicAdd(s_cnt, 1); if (p < MAXDEG) { cols[base + p] = c4 * 4 + 1; vals[base + p] = v.y; } }
      if (v.z != 0.f) { int p = atomicAdd(s_cnt, 1); if (p < MAXDEG) { cols[base + p] = c4 * 4 + 2; vals[base + p] = v.z; } }
      if (v.w != 0.f) { int p = atomicAdd(s_cnt, 1); if (p < MAXDEG) { cols[base + p] = c4 * 4 + 3; vals[base + p] = v.w; } }
    }
    for (int off = 32; off > 0; off >>= 1) sum += __shfl_down(sum, off, 64);
    int wave = t >> 6;
    if ((t & 63) == 0) s_part[wave] = sum;
    __syncthreads();
    if (t == 0) {
      float tot = s_part[0] + s_part[1] + s_part[2] + s_part[3];
      dinv[row] = rsqrtf(tot);
      int c = *s_cnt;
      nnz[row] = (c > MAXDEG) ? MAXDEG : c;
    }
    return;
  }

  // ---------------- GEMM path: 128x64 tile, BK=64, bf16 MFMA ----------------
  unsigned short* As = (unsigned short*)smem;              // [128][64] bf16
  unsigned short* Bs = (unsigned short*)(smem + 16 * 1024); // [64][64] bf16 (B^T)
  int mb = blockIdx.x & 63, nb = blockIdx.x >> 6;
  int m0 = mb * 128, n0 = nb * 64;
  int w = t >> 6, l = t & 63;

  f32x4 acc[2][4] = {};

  for (int kt = 0; kt < EMB; kt += 64) {
    __syncthreads();  // previous tile's reads done
    // stage A: X[m0..m0+128][kt..kt+64] f32 -> bf16, swizzled
    {
      int c4 = t & 15;
#pragma unroll
      for (int rr = 0; rr < 8; rr++) {
        int row = rr * 16 + (t >> 4);
        float4 v = *(const float4*)&X[(size_t)(m0 + row) * EMB + kt + c4 * 4];
        u16x4 pk = {f2bf(v.x), f2bf(v.y), f2bf(v.z), f2bf(v.w)};
        int slot = ((c4 >> 1) + (row >> 1)) & 7;
        *(u16x4*)&As[row * 64 + slot * 8 + (c4 & 1) * 4] = pk;
      }
    }
    // stage B^T from Wt (already bf16, contiguous K)
    {
      int n = t >> 2, q = t & 3;
      const unsigned short* src = &Wt[(size_t)(n0 + n) * EMB + kt + q * 16];
#pragma unroll
      for (int e = 0; e < 2; e++) {
        u16x8 v = *(const u16x8*)(src + e * 8);
        int slot = ((q * 2 + e) + (n >> 1)) & 7;
        *(u16x8*)&Bs[n * 64 + slot * 8] = v;
      }
    }
    __syncthreads();
#pragma unroll
    for (int ks = 0; ks < 2; ks++) {
      bf16x8v a[2], b[4];
#pragma unroll
      for (int mf = 0; mf < 2; mf++) {
        int row = w * 32 + mf * 16 + (l & 15);
        int slot = ((ks * 4 + (l >> 4)) + (row >> 1)) & 7;
        a[mf] = *(bf16x8v*)&As[row * 64 + slot * 8];
      }
#pragma unroll
      for (int nf = 0; nf < 4; nf++) {
        int rowB = nf * 16 + (l & 15);
        int slot = ((ks * 4 + (l >> 4)) + (rowB >> 1)) & 7;
        b[nf] = *(bf16x8v*)&Bs[rowB * 64 + slot * 8];
      }
#pragma unroll
      for (int mf = 0; mf < 2; mf++)
#pragma unroll
        for (int nf = 0; nf < 4; nf++)
          acc[mf][nf] = __builtin_amdgcn_mfma_f32_16x16x32_bf16(a[mf], b[nf], acc[mf][nf], 0, 0, 0);
    }
  }
  // epilogue: bias + relu
#pragma unroll
  for (int mf = 0; mf < 2; mf++)
#pragma unroll
    for (int nf = 0; nf < 4; nf++) {
      int r0 = m0 + w * 32 + mf * 16 + (l >> 4) * 4;
      int cc = n0 + nf * 16 + (l & 15);
      float bv = bias[cc];
#pragma unroll
      for (int r = 0; r < 4; r++)
        h0[(size_t)(r0 + r) * HID + cc] = fmaxf(acc[mf][nf][r] + bv, 0.f);
    }
}

// ---------------------------------------------------------------------------
// Cooperative propagation: all 6 APPNP steps in one kernel.
// 512 blocks x 256 threads; each wave owns 4 rows; h_self and h0 cached in
// registers across steps; grid.sync() between steps.
// ---------------------------------------------------------------------------
__global__ __launch_bounds__(256) void prop_coop(
    const float* __restrict__ h0, float* __restrict__ htmp,
    float* __restrict__ out, const float* __restrict__ dinv,
    const int* __restrict__ nnz, const int* __restrict__ cols,
    const float* __restrict__ vals) {
  cg::grid_group grid = cg::this_grid();
  int w = threadIdx.x >> 6, l = threadIdx.x & 63;
  int wid = blockIdx.x * 4 + w;  // 0..2047, 4 rows each

  float4 hself[4], h0v[4];
  float di[4];
  int nn[4];
#pragma unroll
  for (int r = 0; r < 4; r++) {
    int row = wid * 4 + r;
    h0v[r] = *(const float4*)&h0[(size_t)row * HID + l * 4];
    hself[r] = h0v[r];
    di[r] = dinv[row];
    nn[r] = nnz[row];
  }

  const float* src = h0;
  for (int s = 0; s < 6; s++) {
    float* dst = (s & 1) ? out : htmp;
#pragma unroll
    for (int r = 0; r < 4; r++) {
      int row = wid * 4 + r;
      float ax = 0.f, ay = 0.f, az = 0.f, aw = 0.f;
      int base = row * MAXDEG;
      for (int k = 0; k < nn[r]; k++) {
        int c = cols[base + k];
        float wgt = vals[base + k] * dinv[c];
        float4 hv;
        if (c == row) hv = hself[r];
        else hv = *(const float4*)&src[(size_t)c * HID + l * 4];
        ax += wgt * hv.x; ay += wgt * hv.y; az += wgt * hv.z; aw += wgt * hv.w;
      }
      float sc = 0.8f * di[r];
      float4 o;
      o.x = sc * ax + 0.2f * h0v[r].x;
      o.y = sc * ay + 0.2f * h0v[r].y;
      o.z = sc * az + 0.2f * h0v[r].z;
      o.w = sc * aw + 0.2f * h0v[r].w;
      *(float4*)&dst[(size_t)row * HID + l * 4] = o;
      hself[r] = o;
    }
    src = dst;
    if (s != 5) grid.sync();
  }
}

// ---------------------------------------------------------------------------
extern "C" void kernel_launch(void* const* d_in, const int* in_sizes, int n_in,
                              void* d_out, int out_size, void* d_ws, size_t ws_size,
                              hipStream_t stream) {
  const float* X    = (const float*)d_in[0];  // [8192,1024]
  const float* W    = (const float*)d_in[1];  // [1024,256]
  const float* bias = (const float*)d_in[2];  // [256]
  const float* adj  = (const float*)d_in[3];  // [8192,8192]
  float* out = (float*)d_out;                 // [8192,256]

  char* ws = (char*)d_ws;
  float* h0   = (float*)(ws);                                        // 8 MB
  float* htmp = (float*)(ws + (size_t)8 * 1024 * 1024);              // 8 MB
  float* dinv = (float*)(ws + (size_t)16 * 1024 * 1024);             // 32 KB
  int*   nnz  = (int*)  (ws + (size_t)16 * 1024 * 1024 + 32 * 1024); // 32 KB
  int*   cols = (int*)  (ws + (size_t)16 * 1024 * 1024 + 64 * 1024); // 4 MB
  float* vals = (float*)(ws + (size_t)16 * 1024 * 1024 + 64 * 1024
                            + (size_t)4 * 1024 * 1024);              // 4 MB
  unsigned short* Wt = (unsigned short*)(ws + (size_t)24 * 1024 * 1024
                                            + 64 * 1024);            // 512 KB

  prep_wt<<<64, 256, 0, stream>>>(W, Wt);
  fused_extract_gemm<<<GEMM_BLOCKS + NNODES, 256, 0, stream>>>(
      X, Wt, bias, adj, h0, dinv, nnz, cols, vals);

  void* args[] = {(void*)&h0, (void*)&htmp, (void*)&out, (void*)&dinv,
                  (void*)&nnz, (void*)&cols, (void*)&vals};
  hipLaunchCooperativeKernel((void*)prop_coop, dim3(512), dim3(256),
                             args, 0, stream);
}

// Round 3
// 140.641 us; speedup vs baseline: 3.6884x; 3.6884x over previous
//
#include <hip/hip_runtime.h>
#include <hip/hip_bf16.h>

#define NNODES 8192
#define EMB    1024
#define HID    256
#define MAXDEG 128

typedef float f32x4 __attribute__((ext_vector_type(4)));
typedef short bf16x8v __attribute__((ext_vector_type(8)));
typedef unsigned short u16x4 __attribute__((ext_vector_type(4)));
typedef unsigned short u16x8 __attribute__((ext_vector_type(8)));

static __device__ __forceinline__ unsigned short f2bf(float f) {
  union { float f; unsigned int u; } x; x.f = f;
  unsigned int r = (x.u + 0x7fffu + ((x.u >> 16) & 1u)) >> 16;
  return (unsigned short)r;
}

// ---------------------------------------------------------------------------
// Prep: Wt[n][k] = bf16(W[k][n]).  64x64 f32 tiles via LDS transpose.
// ---------------------------------------------------------------------------
__global__ __launch_bounds__(256) void prep_wt(const float* __restrict__ W,
                                               unsigned short* __restrict__ Wt) {
  __shared__ float lds[64 * 65];
  int k0 = (blockIdx.x >> 2) * 64;
  int n0 = (blockIdx.x & 3) * 64;
  int t = threadIdx.x;
#pragma unroll
  for (int p = 0; p < 4; p++) {
    int k = p * 16 + (t >> 4);
    int c4 = (t & 15) * 4;
    float4 v = *(const float4*)&W[(size_t)(k0 + k) * HID + n0 + c4];
    lds[k * 65 + c4 + 0] = v.x; lds[k * 65 + c4 + 1] = v.y;
    lds[k * 65 + c4 + 2] = v.z; lds[k * 65 + c4 + 3] = v.w;
  }
  __syncthreads();
  int n = t >> 2, kq = t & 3;
  u16x8 o0, o1;
#pragma unroll
  for (int i = 0; i < 8; i++) o0[i] = f2bf(lds[(kq * 16 + i) * 65 + n]);
#pragma unroll
  for (int i = 0; i < 8; i++) o1[i] = f2bf(lds[(kq * 16 + 8 + i) * 65 + n]);
  unsigned short* dst = &Wt[(size_t)(n0 + n) * EMB + k0 + kq * 16];
  *(u16x8*)(dst) = o0;
  *(u16x8*)(dst + 8) = o1;
}

// ---------------------------------------------------------------------------
// Fused: blocks [0,256) = bf16-MFMA GEMM h0 = relu(X@W+b);
// blocks [256, 256+8192) = adjacency extract (one adj row each).
// ---------------------------------------------------------------------------
#define GEMM_BLOCKS 256

__global__ __launch_bounds__(256) void fused_extract_gemm(
    const float* __restrict__ X, const unsigned short* __restrict__ Wt,
    const float* __restrict__ bias, const float* __restrict__ adj,
    float* __restrict__ h0, float* __restrict__ dinv, int* __restrict__ nnz,
    int* __restrict__ cols, float* __restrict__ vals) {
  __shared__ char smem[24 * 1024 + 64];
  int t = threadIdx.x;

  if (blockIdx.x >= GEMM_BLOCKS) {
    // ---------------- extract path ----------------
    int row = blockIdx.x - GEMM_BLOCKS;
    int* s_cnt = (int*)smem;
    float* s_part = (float*)(smem + 16);
    if (t == 0) *s_cnt = 0;
    __syncthreads();
    const float4* arow = (const float4*)(adj + (size_t)row * NNODES);
    float sum = 0.f;
    int base = row * MAXDEG;
    for (int c4 = t; c4 < NNODES / 4; c4 += 256) {
      float4 v = arow[c4];
      sum += v.x + v.y + v.z + v.w;
      if (v.x != 0.f) { int p = atomicAdd(s_cnt, 1); if (p < MAXDEG) { cols[base + p] = c4 * 4 + 0; vals[base + p] = v.x; } }
      if (v.y != 0.f) { int p = atomicAdd(s_cnt, 1); if (p < MAXDEG) { cols[base + p] = c4 * 4 + 1; vals[base + p] = v.y; } }
      if (v.z != 0.f) { int p = atomicAdd(s_cnt, 1); if (p < MAXDEG) { cols[base + p] = c4 * 4 + 2; vals[base + p] = v.z; } }
      if (v.w != 0.f) { int p = atomicAdd(s_cnt, 1); if (p < MAXDEG) { cols[base + p] = c4 * 4 + 3; vals[base + p] = v.w; } }
    }
    for (int off = 32; off > 0; off >>= 1) sum += __shfl_down(sum, off, 64);
    int wave = t >> 6;
    if ((t & 63) == 0) s_part[wave] = sum;
    __syncthreads();
    if (t == 0) {
      float tot = s_part[0] + s_part[1] + s_part[2] + s_part[3];
      dinv[row] = rsqrtf(tot);
      int c = *s_cnt;
      nnz[row] = (c > MAXDEG) ? MAXDEG : c;
    }
    return;
  }

  // ---------------- GEMM path: 128x64 tile, BK=64, bf16 MFMA ----------------
  unsigned short* As = (unsigned short*)smem;               // [128][64] bf16
  unsigned short* Bs = (unsigned short*)(smem + 16 * 1024); // [64][64] bf16 (B^T)
  int mb = blockIdx.x & 63, nb = blockIdx.x >> 6;
  int m0 = mb * 128, n0 = nb * 64;
  int w = t >> 6, l = t & 63;

  f32x4 acc[2][4] = {};

  for (int kt = 0; kt < EMB; kt += 64) {
    __syncthreads();
    {
      int c4 = t & 15;
#pragma unroll
      for (int rr = 0; rr < 8; rr++) {
        int row = rr * 16 + (t >> 4);
        float4 v = *(const float4*)&X[(size_t)(m0 + row) * EMB + kt + c4 * 4];
        u16x4 pk = {f2bf(v.x), f2bf(v.y), f2bf(v.z), f2bf(v.w)};
        int slot = ((c4 >> 1) + (row >> 1)) & 7;
        *(u16x4*)&As[row * 64 + slot * 8 + (c4 & 1) * 4] = pk;
      }
    }
    {
      int n = t >> 2, q = t & 3;
      const unsigned short* src = &Wt[(size_t)(n0 + n) * EMB + kt + q * 16];
#pragma unroll
      for (int e = 0; e < 2; e++) {
        u16x8 v = *(const u16x8*)(src + e * 8);
        int slot = ((q * 2 + e) + (n >> 1)) & 7;
        *(u16x8*)&Bs[n * 64 + slot * 8] = v;
      }
    }
    __syncthreads();
#pragma unroll
    for (int ks = 0; ks < 2; ks++) {
      bf16x8v a[2], b[4];
#pragma unroll
      for (int mf = 0; mf < 2; mf++) {
        int row = w * 32 + mf * 16 + (l & 15);
        int slot = ((ks * 4 + (l >> 4)) + (row >> 1)) & 7;
        a[mf] = *(bf16x8v*)&As[row * 64 + slot * 8];
      }
#pragma unroll
      for (int nf = 0; nf < 4; nf++) {
        int rowB = nf * 16 + (l & 15);
        int slot = ((ks * 4 + (l >> 4)) + (rowB >> 1)) & 7;
        b[nf] = *(bf16x8v*)&Bs[rowB * 64 + slot * 8];
      }
#pragma unroll
      for (int mf = 0; mf < 2; mf++)
#pragma unroll
        for (int nf = 0; nf < 4; nf++)
          acc[mf][nf] = __builtin_amdgcn_mfma_f32_16x16x32_bf16(a[mf], b[nf], acc[mf][nf], 0, 0, 0);
    }
  }
#pragma unroll
  for (int mf = 0; mf < 2; mf++)
#pragma unroll
    for (int nf = 0; nf < 4; nf++) {
      int r0 = m0 + w * 32 + mf * 16 + (l >> 4) * 4;
      int cc = n0 + nf * 16 + (l & 15);
      float bv = bias[cc];
#pragma unroll
      for (int r = 0; r < 4; r++)
        h0[(size_t)(r0 + r) * HID + cc] = fmaxf(acc[mf][nf][r] + bv, 0.f);
    }
}

// ---------------------------------------------------------------------------
// Finalize: fold 0.8 * dinv[row] * dinv[col] into vals, in place.
// One thread per (row, slot); 8192*128 threads.
// ---------------------------------------------------------------------------
__global__ __launch_bounds__(256) void finalize_wgt(
    const float* __restrict__ dinv, const int* __restrict__ nnz,
    const int* __restrict__ cols, float* __restrict__ vals) {
  int e = blockIdx.x * 256 + threadIdx.x;
  int row = e >> 7, k = e & 127;
  if (k < nnz[row]) {
    int c = cols[e];
    vals[e] = 0.8f * dinv[row] * vals[e] * dinv[c];
  }
}

// ---------------------------------------------------------------------------
// One APPNP step: out[row,:] = sum_k wgt[row,k]*h_in[cols[row,k],:] + 0.2*h0[row,:]
// One wave per row; lane = 4 features (float4).
// ---------------------------------------------------------------------------
__global__ __launch_bounds__(256) void prop_step(
    const float* __restrict__ h_in, const float* __restrict__ h0,
    float* __restrict__ h_out, const int* __restrict__ nnz,
    const int* __restrict__ cols, const float* __restrict__ wgt) {
  int wave = threadIdx.x >> 6;
  int lane = threadIdx.x & 63;
  int row = blockIdx.x * 4 + wave;

  int n = nnz[row];
  int base = row * MAXDEG;

  float4 acc = {0.f, 0.f, 0.f, 0.f};
  for (int k = 0; k < n; k++) {
    int j = cols[base + k];
    float w = wgt[base + k];
    float4 hv = *(const float4*)&h_in[(size_t)j * HID + lane * 4];
    acc.x += w * hv.x; acc.y += w * hv.y;
    acc.z += w * hv.z; acc.w += w * hv.w;
  }
  float4 h0v = *(const float4*)&h0[(size_t)row * HID + lane * 4];
  float4 o;
  o.x = acc.x + 0.2f * h0v.x;
  o.y = acc.y + 0.2f * h0v.y;
  o.z = acc.z + 0.2f * h0v.z;
  o.w = acc.w + 0.2f * h0v.w;
  *(float4*)&h_out[(size_t)row * HID + lane * 4] = o;
}

// ---------------------------------------------------------------------------
extern "C" void kernel_launch(void* const* d_in, const int* in_sizes, int n_in,
                              void* d_out, int out_size, void* d_ws, size_t ws_size,
                              hipStream_t stream) {
  const float* X    = (const float*)d_in[0];  // [8192,1024]
  const float* W    = (const float*)d_in[1];  // [1024,256]
  const float* bias = (const float*)d_in[2];  // [256]
  const float* adj  = (const float*)d_in[3];  // [8192,8192]
  float* out = (float*)d_out;                 // [8192,256]

  char* ws = (char*)d_ws;
  float* h0   = (float*)(ws);                                        // 8 MB
  float* htmp = (float*)(ws + (size_t)8 * 1024 * 1024);              // 8 MB
  float* dinv = (float*)(ws + (size_t)16 * 1024 * 1024);             // 32 KB
  int*   nnz  = (int*)  (ws + (size_t)16 * 1024 * 1024 + 32 * 1024); // 32 KB
  int*   cols = (int*)  (ws + (size_t)16 * 1024 * 1024 + 64 * 1024); // 4 MB
  float* vals = (float*)(ws + (size_t)16 * 1024 * 1024 + 64 * 1024
                            + (size_t)4 * 1024 * 1024);              // 4 MB
  unsigned short* Wt = (unsigned short*)(ws + (size_t)24 * 1024 * 1024
                                            + 64 * 1024);            // 512 KB

  prep_wt<<<64, 256, 0, stream>>>(W, Wt);
  fused_extract_gemm<<<GEMM_BLOCKS + NNODES, 256, 0, stream>>>(
      X, Wt, bias, adj, h0, dinv, nnz, cols, vals);
  finalize_wgt<<<NNODES * MAXDEG / 256, 256, 0, stream>>>(dinv, nnz, cols, vals);

  const float* src = h0;
  float* dsts[6] = {htmp, out, htmp, out, htmp, out};
  for (int it = 0; it < 6; it++) {
    prop_step<<<NNODES / 4, 256, 0, stream>>>(src, h0, dsts[it], nnz, cols, vals);
    src = dsts[it];
  }
}